// Round 1
// baseline (1961.214 us; speedup 1.0000x reference)
//
#include <hip/hip_runtime.h>
#include <cmath>

#define NANCH 36864
#define NPRE 6000
#define NPOST 300
#define SEL_CAP 7680

// ---- output (float) offsets ----
#define LOCS_OFF   0
#define SCORES_OFF 294912
#define ROIS_OFF   442368
#define RIDX_OFF   444768
#define ANCH_OFF   445368

// ---- workspace byte offsets ----
#define WT_OFF      0ull          // 9*512*512*4   = 9437184
#define H_OFF       9437184ull    // 2*512*4096*4  = 16777216
#define BOXES_OFF   26214400ull   // 2*36864*16    = 1179648
#define KEYS_OFF    27394048ull   // 2*36864*8     = 589824
#define HIST_OFF    27983872ull   // 2*65536*4     = 524288
#define CNTS_OFF    28508160ull   // 64
#define SCAN_OFF    28508224ull   // 64
#define SEL_OFF     28508288ull   // 2*7680*8      = 122880
#define SKEYS_OFF   28631168ull   // 2*6000*8      = 96000
#define SBOXES_OFF  28727168ull   // 2*6000*16     = 192000

// =====================================================================
// Weight transpose: w[co][ci][kk] -> wt[kk][ci][co]  (coalesced B loads)
// =====================================================================
__global__ __launch_bounds__(1024) void transpose_w_kernel(
    const float* __restrict__ w, float* __restrict__ wt) {
  __shared__ float lds[9][32][33];
  int tx = threadIdx.x;   // ci_local on load, co_local on store
  int ty = threadIdx.y;   // co_local on load, ci_local on store
  int ci0 = blockIdx.x * 32;
  int co0 = blockIdx.y * 32;
  const float* src = w + ((size_t)(co0 + ty) * 512 + (ci0 + tx)) * 9;
#pragma unroll
  for (int k = 0; k < 9; k++) lds[k][tx][ty] = src[k];
  __syncthreads();
#pragma unroll
  for (int k = 0; k < 9; k++) {
    wt[((size_t)k * 512 + (ci0 + ty)) * 512 + co0 + tx] = lds[k][ty][tx];
  }
}

// =====================================================================
// conv1: 3x3, 512->512, pad 1, ReLU, bias.  Implicit GEMM.
// Block: 256 threads, tile 64(x) x 64(co), 4x4 micro-tile per thread.
// grid.x = n*64+y (128), grid.y = co/64 (8)
// =====================================================================
__global__ __launch_bounds__(256) void conv1_kernel(
    const float* __restrict__ x, const float* __restrict__ wt,
    const float* __restrict__ bias, float* __restrict__ hout) {
  __shared__ __align__(16) float At[16][64];
  __shared__ __align__(16) float Bt[16][64];
  int mb = blockIdx.x;
  int n = mb >> 6, y = mb & 63;
  int co0 = blockIdx.y * 64;
  int tid = threadIdx.x;
  int tx = tid & 15, ty = tid >> 4;
  int lr = tid >> 4;            // load row 0..15
  int lc = (tid & 15) * 4;      // load col group
  float acc[4][4];
#pragma unroll
  for (int j = 0; j < 4; j++)
#pragma unroll
    for (int i = 0; i < 4; i++) acc[j][i] = 0.f;

  const float* xbase = x + (size_t)n * 512 * 4096;

  for (int kk = 0; kk < 9; kk++) {
    int ky = kk / 3, kx = kk - ky * 3;
    int ys = y + ky - 1;
    if (ys < 0 || ys >= 64) continue;   // uniform per block
    for (int ci0 = 0; ci0 < 512; ci0 += 16) {
      const float* row = xbase + ((size_t)(ci0 + lr) * 64 + ys) * 64;
#pragma unroll
      for (int i2 = 0; i2 < 4; i2++) {
        int xs = lc + i2 + kx - 1;
        At[lr][lc + i2] = (xs >= 0 && xs < 64) ? row[xs] : 0.f;
      }
      *(float4*)&Bt[lr][lc] =
          *(const float4*)(wt + ((size_t)kk * 512 + ci0 + lr) * 512 + co0 + lc);
      __syncthreads();
#pragma unroll
      for (int k = 0; k < 16; k++) {
        float4 av = *(const float4*)&At[k][tx << 2];
        float4 bv = *(const float4*)&Bt[k][ty << 2];
        float a_[4] = {av.x, av.y, av.z, av.w};
        float b_[4] = {bv.x, bv.y, bv.z, bv.w};
#pragma unroll
        for (int j = 0; j < 4; j++)
#pragma unroll
          for (int i2 = 0; i2 < 4; i2++) acc[j][i2] += a_[i2] * b_[j];
      }
      __syncthreads();
    }
  }
#pragma unroll
  for (int j = 0; j < 4; j++) {
    int co = co0 + (ty << 2) + j;
    float bb = bias[co];
    float4 v;
    v.x = fmaxf(acc[j][0] + bb, 0.f);
    v.y = fmaxf(acc[j][1] + bb, 0.f);
    v.z = fmaxf(acc[j][2] + bb, 0.f);
    v.w = fmaxf(acc[j][3] + bb, 0.f);
    *(float4*)(hout + (((size_t)n * 512 + co) * 64 + y) * 64 + (tx << 2)) = v;
  }
}

// =====================================================================
// 1x1 convs: loc (36ch) + score (18ch), written in transposed layouts.
// Block: 512 threads = 64 x-positions * 8 lanes; grid = 128 (n*64+y).
// =====================================================================
__global__ __launch_bounds__(512) void conv1x1_kernel(
    const float* __restrict__ h, const float* __restrict__ score_w,
    const float* __restrict__ score_b, const float* __restrict__ loc_w,
    const float* __restrict__ loc_b, float* __restrict__ out) {
  int blk = blockIdx.x;
  int n = blk >> 6, y = blk & 63;
  int tid = threadIdx.x;
  int x = tid & 63;
  int c = tid >> 6;          // 0..7
  const float* wrow[7];
  int cos[7];
  int nco = 0;
#pragma unroll
  for (int j = 0; j < 7; j++) {
    int co = c + 8 * j;
    if (co < 54) {
      cos[nco] = co;
      wrow[nco] = (co < 36) ? (loc_w + (size_t)co * 512)
                            : (score_w + (size_t)(co - 36) * 512);
      nco++;
    }
  }
  float acc[7];
#pragma unroll
  for (int j = 0; j < 7; j++) acc[j] = 0.f;
  const float* hbase = h + (size_t)n * 512 * 4096 + (size_t)y * 64 + x;
  for (int ci = 0; ci < 512; ci++) {
    float hv = hbase[(size_t)ci * 4096];
#pragma unroll
    for (int j = 0; j < 7; j++) {
      if (j < nco) acc[j] = fmaf(hv, wrow[j][ci], acc[j]);
    }
  }
  int p = y * 64 + x;
  for (int j = 0; j < nco; j++) {
    int co = cos[j];
    if (co < 36) {
      float v = acc[j] + loc_b[co];
      out[LOCS_OFF + (((size_t)n * 4096 + p) * 9 + (co >> 2)) * 4 + (co & 3)] = v;
    } else {
      int sc = co - 36;
      float v = acc[j] + score_b[sc];
      out[SCORES_OFF + (((size_t)n * 4096 + p) * 9 + (sc >> 1)) * 2 + (sc & 1)] = v;
    }
  }
}

// =====================================================================
// Anchors (fp64 base rounded once to fp32, matching np)
// =====================================================================
__global__ void anchors_kernel(float* __restrict__ out) {
  int k = blockIdx.x * 256 + threadIdx.x;   // < 36864 exact
  int a = k % 9, pos = k / 9;
  int j = pos & 63, i = pos >> 6;
  int ridx = a / 3, sidx = a % 3;
  double r = (ridx == 0) ? 0.5 : ((ridx == 1) ? 1.0 : 2.0);
  double s = (sidx == 0) ? 8.0 : ((sidx == 1) ? 16.0 : 32.0);
  double hh = 16.0 * s * sqrt(r);
  double ww = 16.0 * s * sqrt(1.0 / r);
  float b0 = (float)(8.0 - hh / 2.0), b1 = (float)(8.0 - ww / 2.0);
  float b2 = (float)(8.0 + hh / 2.0), b3 = (float)(8.0 + ww / 2.0);
  float sy = (float)(i * 16), sx = (float)(j * 16);
  float* o = out + ANCH_OFF + (size_t)k * 4;
  o[0] = sy + b0; o[1] = sx + b1; o[2] = sy + b2; o[3] = sx + b3;
}

// =====================================================================
// Decode: boxes + clip + valid + fg score + sortable key
// key = (~ord_asc(score) << 16) | idx : ascending key == descending score,
// ties by ascending idx (matches lax.top_k / stable argsort)
// =====================================================================
__global__ void decode_kernel(const float* __restrict__ out,
                              const int* __restrict__ pimh,
                              const int* __restrict__ pimw,
                              float* __restrict__ boxes,
                              unsigned long long* __restrict__ keys) {
  int t = blockIdx.x * 256 + threadIdx.x;   // < 73728 exact
  int n = t / NANCH, k = t - n * NANCH;
  float imh = (float)pimh[0], imw = (float)pimw[0];
  const float* an = out + ANCH_OFF + (size_t)k * 4;
  const float* loc = out + LOCS_OFF + (size_t)t * 4;
  const float* sc = out + SCORES_OFF + (size_t)t * 2;
  float a0 = an[0], a1 = an[1], a2 = an[2], a3 = an[3];
  float ah = __fsub_rn(a2, a0), aw = __fsub_rn(a3, a1);
  float acy = __fadd_rn(a0, 0.5f * ah), acx = __fadd_rn(a1, 0.5f * aw);
  float dy = loc[0], dx = loc[1], dh = loc[2], dw = loc[3];
  float cy = __fadd_rn(__fmul_rn(dy, ah), acy);
  float cx = __fadd_rn(__fmul_rn(dx, aw), acx);
  float hh = __fmul_rn(expf(dh), ah);
  float ww = __fmul_rn(expf(dw), aw);
  float y1 = __fsub_rn(cy, 0.5f * hh), x1 = __fsub_rn(cx, 0.5f * ww);
  float y2 = __fadd_rn(cy, 0.5f * hh), x2 = __fadd_rn(cx, 0.5f * ww);
  y1 = fminf(fmaxf(y1, 0.f), imh); x1 = fminf(fmaxf(x1, 0.f), imw);
  y2 = fminf(fmaxf(y2, 0.f), imh); x2 = fminf(fmaxf(x2, 0.f), imw);
  bool valid = (__fsub_rn(y2, y1) >= 16.f) && (__fsub_rn(x2, x1) >= 16.f);
  float s0 = sc[0], s1 = sc[1];
  float m = fmaxf(s0, s1);
  float e0 = expf(__fsub_rn(s0, m)), e1 = expf(__fsub_rn(s1, m));
  float fg = __fdiv_rn(e1, __fadd_rn(e0, e1));
  float score = valid ? fg : -INFINITY;
  unsigned int u = __float_as_uint(score);
  unsigned int ord = (u & 0x80000000u) ? ~u : (u | 0x80000000u);
  unsigned long long key =
      ((unsigned long long)(~ord) << 16) | (unsigned long long)(k & 0xFFFF);
  float4 b4; b4.x = y1; b4.y = x1; b4.z = y2; b4.w = x2;
  *(float4*)(boxes + (size_t)t * 4) = b4;
  keys[t] = key;
}

// =====================================================================
// Histogram on top-16 key bits (per batch)
// =====================================================================
__global__ void hist_kernel(const unsigned long long* __restrict__ keys,
                            unsigned int* __restrict__ hist) {
  int t = blockIdx.x * 256 + threadIdx.x;
  int n = t / NANCH;
  unsigned int b = (unsigned int)(keys[t] >> 32);
  atomicAdd(&hist[(size_t)n * 65536 + b], 1u);
}

// =====================================================================
// Scan: find cutoff bucket b* (smallest with cum >= 6000) per batch
// =====================================================================
__global__ __launch_bounds__(1024) void scan_kernel(
    const unsigned int* __restrict__ hist, int* __restrict__ scaninfo) {
  __shared__ unsigned int ps[1024];
  int tid = threadIdx.x;
  for (int n = 0; n < 2; n++) {
    const unsigned int* h = hist + (size_t)n * 65536;
    int base = tid * 64;
    unsigned int s = 0;
    for (int i = 0; i < 64; i++) s += h[base + i];
    ps[tid] = s;
    __syncthreads();
    for (int off = 1; off < 1024; off <<= 1) {
      unsigned int v = ps[tid];
      unsigned int add = (tid >= off) ? ps[tid - off] : 0u;
      __syncthreads();
      ps[tid] = v + add;
      __syncthreads();
    }
    unsigned int incl = ps[tid];
    unsigned int excl = incl - s;
    if (excl < (unsigned)NPRE && incl >= (unsigned)NPRE) {
      unsigned int c = excl;
      for (int i = 0; i < 64; i++) {
        unsigned int hv = h[base + i];
        if (c + hv >= (unsigned)NPRE) {
          scaninfo[n * 2] = base + i;
          scaninfo[n * 2 + 1] = (int)c;
          break;
        }
        c += hv;
      }
    }
    __syncthreads();
  }
}

// =====================================================================
// Compact: bucket < b* -> slots [0,C0); bucket == b* -> slots [6000,CAP)
// (unfilled slots pre-set to 0xFF..FF == invalid MAX keys)
// =====================================================================
__global__ void compact_kernel(const unsigned long long* __restrict__ keys,
                               const int* __restrict__ scaninfo,
                               unsigned int* __restrict__ cnts,
                               unsigned long long* __restrict__ sel) {
  int t = blockIdx.x * 256 + threadIdx.x;
  int n = t / NANCH;
  unsigned long long key = keys[t];
  int b = (int)(unsigned int)(key >> 32);
  int bstar = scaninfo[n * 2];
  if (b < bstar) {
    unsigned int p = atomicAdd(&cnts[n * 2], 1u);
    sel[(size_t)n * SEL_CAP + p] = key;
  } else if (b == bstar) {
    unsigned int p = (unsigned)NPRE + atomicAdd(&cnts[n * 2 + 1], 1u);
    if (p < (unsigned)SEL_CAP) sel[(size_t)n * SEL_CAP + p] = key;
  }
}

// =====================================================================
// Rank: exact global rank by counting (keys unique), scatter top-6000
// sorted keys + gather boxes.  grid (8, 2) x 960 threads.
// =====================================================================
__global__ __launch_bounds__(960) void rank_kernel(
    const unsigned long long* __restrict__ sel,
    const float* __restrict__ boxes,
    unsigned long long* __restrict__ skeys, float* __restrict__ sboxes) {
  int n = blockIdx.y;
  const unsigned long long* s = sel + (size_t)n * SEL_CAP;
  __shared__ unsigned long long lds[SEL_CAP];
  int tid = threadIdx.x;
  for (int i = tid; i < SEL_CAP; i += 960) lds[i] = s[i];
  __syncthreads();
  int e = blockIdx.x * 960 + tid;
  unsigned long long my = lds[e];
  int r = 0;
#pragma unroll 8
  for (int j = 0; j < SEL_CAP; j++) r += (lds[j] < my) ? 1 : 0;
  if (r < NPRE) {
    skeys[(size_t)n * NPRE + r] = my;
    unsigned int hi = (unsigned int)(my >> 16);
    if (hi < 0xFF800000u) {
      int k = (int)(my & 0xFFFFull);
      float4 bx = *(const float4*)(boxes + ((size_t)n * NANCH + k) * 4);
      *(float4*)(sboxes + ((size_t)n * NPRE + r) * 4) = bx;
    }
  }
}

// =====================================================================
// Greedy NMS with ballot skip-ahead; writes rois + roi_indices.
// grid = 2 blocks (one per batch), 1024 threads.
// =====================================================================
__global__ __launch_bounds__(1024) void nms_kernel(
    const unsigned long long* __restrict__ skeys,
    const float* __restrict__ sboxes, float* __restrict__ out) {
  int n = blockIdx.x;
  const unsigned long long* keys = skeys + (size_t)n * NPRE;
  const float* boxes = sboxes + (size_t)n * NPRE * 4;
  float* rois = out + ROIS_OFF + (size_t)n * NPOST * 4;
  float* ridx = out + RIDX_OFF + (size_t)n * NPOST;
  __shared__ unsigned char keep[NPRE];
  __shared__ unsigned long long ball[16];
  __shared__ int s_next;
  int tid = threadIdx.x;
  for (int i = tid; i < NPRE; i += 1024) {
    unsigned int hi = (unsigned int)(keys[i] >> 16);
    keep[i] = (hi < 0xFF800000u) ? 1 : 0;
  }
  for (int i = tid; i < NPOST * 4; i += 1024) rois[i] = 0.f;
  for (int i = tid; i < NPOST; i += 1024) ridx[i] = (float)n;
  __syncthreads();

  int count = 0;
  int i = 0;
  while (i < NPRE && count < NPOST) {
    // find next kept index >= i
    int idx = i + tid;
    bool f = (idx < NPRE) && keep[idx];
    unsigned long long b = __ballot(f);
    if ((tid & 63) == 0) ball[tid >> 6] = b;
    __syncthreads();
    if (tid == 0) {
      int nx = -1;
      for (int w = 0; w < 16; w++) {
        if (ball[w]) { nx = i + w * 64 + __ffsll(ball[w]) - 1; break; }
      }
      s_next = nx;
    }
    __syncthreads();
    int ni = s_next;
    if (ni < 0) { i += 1024; continue; }
    i = ni;
    float4 bi = *(const float4*)(boxes + (size_t)i * 4);
    if (tid < 4) {
      const float* pb = (const float*)&bi;
      rois[count * 4 + tid] = pb[tid];
    }
    count++;
    if (count >= NPOST) break;
    float ay1 = bi.x, ax1 = bi.y, ay2 = bi.z, ax2 = bi.w;
    float areaA = __fmul_rn(__fsub_rn(ay2, ay1), __fsub_rn(ax2, ax1));
    for (int j = i + 1 + tid; j < NPRE; j += 1024) {
      if (!keep[j]) continue;
      float4 bj = *(const float4*)(boxes + (size_t)j * 4);
      float ty1 = fmaxf(ay1, bj.x), tx1 = fmaxf(ax1, bj.y);
      float ty2 = fminf(ay2, bj.z), tx2 = fminf(ax2, bj.w);
      float wh0 = fmaxf(__fsub_rn(ty2, ty1), 0.f);
      float wh1 = fmaxf(__fsub_rn(tx2, tx1), 0.f);
      float inter = __fmul_rn(wh0, wh1);
      float areaB = __fmul_rn(__fsub_rn(bj.z, bj.x), __fsub_rn(bj.w, bj.y));
      float den = __fadd_rn(__fsub_rn(__fadd_rn(areaA, areaB), inter), 1e-9f);
      float iou = __fdiv_rn(inter, den);
      if (iou > 0.7f) keep[j] = 0;
    }
    __syncthreads();
    i = i + 1;
  }
}

// =====================================================================
extern "C" void kernel_launch(void* const* d_in, const int* in_sizes, int n_in,
                              void* d_out, int out_size, void* d_ws,
                              size_t ws_size, hipStream_t stream) {
  const float* feat = (const float*)d_in[0];
  const float* w1 = (const float*)d_in[1];
  const float* b1 = (const float*)d_in[2];
  const float* sw = (const float*)d_in[3];
  const float* sb = (const float*)d_in[4];
  const float* lw = (const float*)d_in[5];
  const float* lb = (const float*)d_in[6];
  const int* pimh = (const int*)d_in[7];
  const int* pimw = (const int*)d_in[8];
  float* out = (float*)d_out;
  char* ws = (char*)d_ws;

  float* wt = (float*)(ws + WT_OFF);
  float* hbuf = (float*)(ws + H_OFF);
  float* boxes = (float*)(ws + BOXES_OFF);
  unsigned long long* keys = (unsigned long long*)(ws + KEYS_OFF);
  unsigned int* hist = (unsigned int*)(ws + HIST_OFF);
  unsigned int* cnts = (unsigned int*)(ws + CNTS_OFF);
  int* scaninfo = (int*)(ws + SCAN_OFF);
  unsigned long long* sel = (unsigned long long*)(ws + SEL_OFF);
  unsigned long long* skeys = (unsigned long long*)(ws + SKEYS_OFF);
  float* sboxes = (float*)(ws + SBOXES_OFF);

  // init: hist + cnts zero; sel + sorted keys -> 0xFF (MAX keys = invalid)
  hipMemsetAsync(ws + HIST_OFF, 0, 524288 + 64, stream);
  hipMemsetAsync(ws + SEL_OFF, 0xFF, 122880 + 96000, stream);

  transpose_w_kernel<<<dim3(16, 16), dim3(32, 32), 0, stream>>>(w1, wt);
  conv1_kernel<<<dim3(128, 8), 256, 0, stream>>>(feat, wt, b1, hbuf);
  conv1x1_kernel<<<128, 512, 0, stream>>>(hbuf, sw, sb, lw, lb, out);
  anchors_kernel<<<144, 256, 0, stream>>>(out);
  decode_kernel<<<288, 256, 0, stream>>>(out, pimh, pimw, boxes, keys);
  hist_kernel<<<288, 256, 0, stream>>>(keys, hist);
  scan_kernel<<<1, 1024, 0, stream>>>(hist, scaninfo);
  compact_kernel<<<288, 256, 0, stream>>>(keys, scaninfo, cnts, sel);
  rank_kernel<<<dim3(8, 2), 960, 0, stream>>>(sel, boxes, skeys, sboxes);
  nms_kernel<<<2, 1024, 0, stream>>>(skeys, sboxes, out);
}

// Round 2
// 1278.685 us; speedup vs baseline: 1.5338x; 1.5338x over previous
//
#include <hip/hip_runtime.h>
#include <cmath>

#define NANCH 36864
#define NPRE 6000
#define NPOST 300
#define SEL_CAP 7680

// ---- output (float) offsets ----
#define LOCS_OFF   0
#define SCORES_OFF 294912
#define ROIS_OFF   442368
#define RIDX_OFF   444768
#define ANCH_OFF   445368

// ---- workspace byte offsets ----
#define WT_OFF      0ull          // 9*512*512*4   = 9437184 (conv1 weights)
#define MASK_OFF    0ull          // reuse: 2*6000*94*8 = 9024000 <= 9437184 (dead after conv1)
#define H_OFF       9437184ull    // 2*512*4096*4  = 16777216
#define BOXES_OFF   26214400ull   // 2*36864*16    = 1179648
#define KEYS_OFF    27394048ull   // 2*36864*8     = 589824
#define HIST_OFF    27983872ull   // 2*65536*4     = 524288
#define CNTS_OFF    28508160ull   // 64
#define SCAN_OFF    28508224ull   // 64
#define SEL_OFF     28508288ull   // 2*7680*8      = 122880
#define SKEYS_OFF   28631168ull   // 2*6000*8      = 96000
#define SBOXES_OFF  28727168ull   // 2*6000*16    = 192000
#define W54_OFF     28919168ull   // 512*56*4      = 114688
#define VMASK_OFF   29033856ull   // 2*94*8        = 1504

// =====================================================================
// Weight transpose: w[co][ci][kk] -> wt[kk][ci][co]  (coalesced B loads)
// =====================================================================
__global__ __launch_bounds__(1024) void transpose_w_kernel(
    const float* __restrict__ w, float* __restrict__ wt) {
  __shared__ float lds[9][32][33];
  int tx = threadIdx.x;
  int ty = threadIdx.y;
  int ci0 = blockIdx.x * 32;
  int co0 = blockIdx.y * 32;
  const float* src = w + ((size_t)(co0 + ty) * 512 + (ci0 + tx)) * 9;
#pragma unroll
  for (int k = 0; k < 9; k++) lds[k][tx][ty] = src[k];
  __syncthreads();
#pragma unroll
  for (int k = 0; k < 9; k++) {
    wt[((size_t)k * 512 + (ci0 + ty)) * 512 + co0 + tx] = lds[k][ty][tx];
  }
}

// =====================================================================
// 1x1 head weights: loc_w[36][512] + score_w[18][512] -> wt54[512][56]
// =====================================================================
__global__ void transpose54_kernel(const float* __restrict__ lw,
                                   const float* __restrict__ sw,
                                   float* __restrict__ wt) {
  int t = blockIdx.x * 256 + threadIdx.x;
  if (t >= 512 * 56) return;
  int k = t / 56, co = t - k * 56;
  float v = 0.f;
  if (co < 36) v = lw[(size_t)co * 512 + k];
  else if (co < 54) v = sw[(size_t)(co - 36) * 512 + k];
  wt[t] = v;
}

// =====================================================================
// conv1: 3x3, 512->512, pad 1, ReLU, bias.  Implicit GEMM (unchanged).
// =====================================================================
__global__ __launch_bounds__(256) void conv1_kernel(
    const float* __restrict__ x, const float* __restrict__ wt,
    const float* __restrict__ bias, float* __restrict__ hout) {
  __shared__ __align__(16) float At[16][64];
  __shared__ __align__(16) float Bt[16][64];
  int mb = blockIdx.x;
  int n = mb >> 6, y = mb & 63;
  int co0 = blockIdx.y * 64;
  int tid = threadIdx.x;
  int tx = tid & 15, ty = tid >> 4;
  int lr = tid >> 4;
  int lc = (tid & 15) * 4;
  float acc[4][4];
#pragma unroll
  for (int j = 0; j < 4; j++)
#pragma unroll
    for (int i = 0; i < 4; i++) acc[j][i] = 0.f;

  const float* xbase = x + (size_t)n * 512 * 4096;

  for (int kk = 0; kk < 9; kk++) {
    int ky = kk / 3, kx = kk - ky * 3;
    int ys = y + ky - 1;
    if (ys < 0 || ys >= 64) continue;
    for (int ci0 = 0; ci0 < 512; ci0 += 16) {
      const float* row = xbase + ((size_t)(ci0 + lr) * 64 + ys) * 64;
#pragma unroll
      for (int i2 = 0; i2 < 4; i2++) {
        int xs = lc + i2 + kx - 1;
        At[lr][lc + i2] = (xs >= 0 && xs < 64) ? row[xs] : 0.f;
      }
      *(float4*)&Bt[lr][lc] =
          *(const float4*)(wt + ((size_t)kk * 512 + ci0 + lr) * 512 + co0 + lc);
      __syncthreads();
#pragma unroll
      for (int k = 0; k < 16; k++) {
        float4 av = *(const float4*)&At[k][tx << 2];
        float4 bv = *(const float4*)&Bt[k][ty << 2];
        float a_[4] = {av.x, av.y, av.z, av.w};
        float b_[4] = {bv.x, bv.y, bv.z, bv.w};
#pragma unroll
        for (int j = 0; j < 4; j++)
#pragma unroll
          for (int i2 = 0; i2 < 4; i2++) acc[j][i2] += a_[i2] * b_[j];
      }
      __syncthreads();
    }
  }
#pragma unroll
  for (int j = 0; j < 4; j++) {
    int co = co0 + (ty << 2) + j;
    float bb = bias[co];
    float4 v;
    v.x = fmaxf(acc[j][0] + bb, 0.f);
    v.y = fmaxf(acc[j][1] + bb, 0.f);
    v.z = fmaxf(acc[j][2] + bb, 0.f);
    v.w = fmaxf(acc[j][3] + bb, 0.f);
    *(float4*)(hout + (((size_t)n * 512 + co) * 64 + y) * 64 + (tx << 2)) = v;
  }
}

// =====================================================================
// 1x1 heads: wave = one position (broadcast h), lane = out channel
// (coalesced wt54 row).  Same ascending-k fma chain as before ->
// bit-identical locs/scores.  grid = 2048 blocks x 256 thr = 8192 waves.
// =====================================================================
__global__ __launch_bounds__(256) void heads_kernel(
    const float* __restrict__ h, const float* __restrict__ wt54,
    const float* __restrict__ loc_b, const float* __restrict__ score_b,
    float* __restrict__ out) {
  int lane = threadIdx.x & 63;
  int sub = threadIdx.x >> 6;
  int gp = blockIdx.x * 4 + sub;         // 0..8191
  int n = gp >> 12, p = gp & 4095;
  const float* hb = h + (size_t)n * 512 * 4096 + p;
  float acc = 0.f;
#pragma unroll 8
  for (int k = 0; k < 512; k++) {
    acc = fmaf(hb[(size_t)k * 4096], wt54[k * 56 + lane], acc);
  }
  if (lane < 36) {
    out[LOCS_OFF + ((size_t)n * 4096 + p) * 36 + lane] = acc + loc_b[lane];
  } else if (lane < 54) {
    int sc = lane - 36;
    out[SCORES_OFF + ((size_t)n * 4096 + p) * 18 + sc] = acc + score_b[sc];
  }
}

// =====================================================================
// Anchors (fp64 base rounded once to fp32, matching np)
// =====================================================================
__global__ void anchors_kernel(float* __restrict__ out) {
  int k = blockIdx.x * 256 + threadIdx.x;
  int a = k % 9, pos = k / 9;
  int j = pos & 63, i = pos >> 6;
  int ridx = a / 3, sidx = a % 3;
  double r = (ridx == 0) ? 0.5 : ((ridx == 1) ? 1.0 : 2.0);
  double s = (sidx == 0) ? 8.0 : ((sidx == 1) ? 16.0 : 32.0);
  double hh = 16.0 * s * sqrt(r);
  double ww = 16.0 * s * sqrt(1.0 / r);
  float b0 = (float)(8.0 - hh / 2.0), b1 = (float)(8.0 - ww / 2.0);
  float b2 = (float)(8.0 + hh / 2.0), b3 = (float)(8.0 + ww / 2.0);
  float sy = (float)(i * 16), sx = (float)(j * 16);
  float* o = out + ANCH_OFF + (size_t)k * 4;
  o[0] = sy + b0; o[1] = sx + b1; o[2] = sy + b2; o[3] = sx + b3;
}

// =====================================================================
// Decode: boxes + clip + valid + fg score + sortable key
// =====================================================================
__global__ void decode_kernel(const float* __restrict__ out,
                              const int* __restrict__ pimh,
                              const int* __restrict__ pimw,
                              float* __restrict__ boxes,
                              unsigned long long* __restrict__ keys) {
  int t = blockIdx.x * 256 + threadIdx.x;
  int n = t / NANCH, k = t - n * NANCH;
  float imh = (float)pimh[0], imw = (float)pimw[0];
  const float* an = out + ANCH_OFF + (size_t)k * 4;
  const float* loc = out + LOCS_OFF + (size_t)t * 4;
  const float* sc = out + SCORES_OFF + (size_t)t * 2;
  float a0 = an[0], a1 = an[1], a2 = an[2], a3 = an[3];
  float ah = __fsub_rn(a2, a0), aw = __fsub_rn(a3, a1);
  float acy = __fadd_rn(a0, 0.5f * ah), acx = __fadd_rn(a1, 0.5f * aw);
  float dy = loc[0], dx = loc[1], dh = loc[2], dw = loc[3];
  float cy = __fadd_rn(__fmul_rn(dy, ah), acy);
  float cx = __fadd_rn(__fmul_rn(dx, aw), acx);
  float hh = __fmul_rn(expf(dh), ah);
  float ww = __fmul_rn(expf(dw), aw);
  float y1 = __fsub_rn(cy, 0.5f * hh), x1 = __fsub_rn(cx, 0.5f * ww);
  float y2 = __fadd_rn(cy, 0.5f * hh), x2 = __fadd_rn(cx, 0.5f * ww);
  y1 = fminf(fmaxf(y1, 0.f), imh); x1 = fminf(fmaxf(x1, 0.f), imw);
  y2 = fminf(fmaxf(y2, 0.f), imh); x2 = fminf(fmaxf(x2, 0.f), imw);
  bool valid = (__fsub_rn(y2, y1) >= 16.f) && (__fsub_rn(x2, x1) >= 16.f);
  float s0 = sc[0], s1 = sc[1];
  float m = fmaxf(s0, s1);
  float e0 = expf(__fsub_rn(s0, m)), e1 = expf(__fsub_rn(s1, m));
  float fg = __fdiv_rn(e1, __fadd_rn(e0, e1));
  float score = valid ? fg : -INFINITY;
  unsigned int u = __float_as_uint(score);
  unsigned int ord = (u & 0x80000000u) ? ~u : (u | 0x80000000u);
  unsigned long long key =
      ((unsigned long long)(~ord) << 16) | (unsigned long long)(k & 0xFFFF);
  float4 b4; b4.x = y1; b4.y = x1; b4.z = y2; b4.w = x2;
  *(float4*)(boxes + (size_t)t * 4) = b4;
  keys[t] = key;
}

// =====================================================================
// Histogram on top-16 key bits (per batch)
// =====================================================================
__global__ void hist_kernel(const unsigned long long* __restrict__ keys,
                            unsigned int* __restrict__ hist) {
  int t = blockIdx.x * 256 + threadIdx.x;
  int n = t / NANCH;
  unsigned int b = (unsigned int)(keys[t] >> 32);
  atomicAdd(&hist[(size_t)n * 65536 + b], 1u);
}

// =====================================================================
// Scan: find cutoff bucket b* per batch
// =====================================================================
__global__ __launch_bounds__(1024) void scan_kernel(
    const unsigned int* __restrict__ hist, int* __restrict__ scaninfo) {
  __shared__ unsigned int ps[1024];
  int tid = threadIdx.x;
  for (int n = 0; n < 2; n++) {
    const unsigned int* h = hist + (size_t)n * 65536;
    int base = tid * 64;
    unsigned int s = 0;
    for (int i = 0; i < 64; i++) s += h[base + i];
    ps[tid] = s;
    __syncthreads();
    for (int off = 1; off < 1024; off <<= 1) {
      unsigned int v = ps[tid];
      unsigned int add = (tid >= off) ? ps[tid - off] : 0u;
      __syncthreads();
      ps[tid] = v + add;
      __syncthreads();
    }
    unsigned int incl = ps[tid];
    unsigned int excl = incl - s;
    if (excl < (unsigned)NPRE && incl >= (unsigned)NPRE) {
      unsigned int c = excl;
      for (int i = 0; i < 64; i++) {
        unsigned int hv = h[base + i];
        if (c + hv >= (unsigned)NPRE) {
          scaninfo[n * 2] = base + i;
          scaninfo[n * 2 + 1] = (int)c;
          break;
        }
        c += hv;
      }
    }
    __syncthreads();
  }
}

// =====================================================================
// Compact
// =====================================================================
__global__ void compact_kernel(const unsigned long long* __restrict__ keys,
                               const int* __restrict__ scaninfo,
                               unsigned int* __restrict__ cnts,
                               unsigned long long* __restrict__ sel) {
  int t = blockIdx.x * 256 + threadIdx.x;
  int n = t / NANCH;
  unsigned long long key = keys[t];
  int b = (int)(unsigned int)(key >> 32);
  int bstar = scaninfo[n * 2];
  if (b < bstar) {
    unsigned int p = atomicAdd(&cnts[n * 2], 1u);
    sel[(size_t)n * SEL_CAP + p] = key;
  } else if (b == bstar) {
    unsigned int p = (unsigned)NPRE + atomicAdd(&cnts[n * 2 + 1], 1u);
    if (p < (unsigned)SEL_CAP) sel[(size_t)n * SEL_CAP + p] = key;
  }
}

// =====================================================================
// Rank: exact global rank by counting
// =====================================================================
__global__ __launch_bounds__(960) void rank_kernel(
    const unsigned long long* __restrict__ sel,
    const float* __restrict__ boxes,
    unsigned long long* __restrict__ skeys, float* __restrict__ sboxes) {
  int n = blockIdx.y;
  const unsigned long long* s = sel + (size_t)n * SEL_CAP;
  __shared__ unsigned long long lds[SEL_CAP];
  int tid = threadIdx.x;
  for (int i = tid; i < SEL_CAP; i += 960) lds[i] = s[i];
  __syncthreads();
  int e = blockIdx.x * 960 + tid;
  unsigned long long my = lds[e];
  int r = 0;
#pragma unroll 8
  for (int j = 0; j < SEL_CAP; j++) r += (lds[j] < my) ? 1 : 0;
  if (r < NPRE) {
    skeys[(size_t)n * NPRE + r] = my;
    unsigned int hi = (unsigned int)(my >> 16);
    if (hi < 0xFF800000u) {
      int k = (int)(my & 0xFFFFull);
      float4 bx = *(const float4*)(boxes + ((size_t)n * NANCH + k) * 4);
      *(float4*)(sboxes + ((size_t)n * NPRE + r) * 4) = bx;
    }
  }
}

// =====================================================================
// Validity bitmask of the 6000 sorted slots: vmask[n][94]
// =====================================================================
__global__ void valid_kernel(const unsigned long long* __restrict__ skeys,
                             unsigned long long* __restrict__ vmask) {
  int n = blockIdx.y;
  int w = blockIdx.x;
  int lane = threadIdx.x;
  int j = w * 64 + lane;
  bool ok = false;
  if (j < NPRE) {
    unsigned int hi = (unsigned int)(skeys[(size_t)n * NPRE + j] >> 16);
    ok = hi < 0xFF800000u;
  }
  unsigned long long m = __ballot(ok);
  if (lane == 0) vmask[(size_t)n * 94 + w] = m;
}

// =====================================================================
// NMS phase A: pairwise suppression bitmask.
// grid (94 iblocks, 94 jblocks, 2 batch), 64 threads.
// mask[(n*6000+i)*94 + jb] bit l = iou(box_i, box_{jb*64+l}) > 0.7
// =====================================================================
__global__ __launch_bounds__(64) void nms_mask_kernel(
    const float* __restrict__ sboxes, unsigned long long* __restrict__ mask) {
  int n = blockIdx.z;
  int ib = blockIdx.x, jb = blockIdx.y;
  int lane = threadIdx.x;
  __shared__ __align__(16) float jbox[64][4];
  int j = jb * 64 + lane;
  float4 bj4 = (j < NPRE)
                   ? *(const float4*)(sboxes + ((size_t)n * NPRE + j) * 4)
                   : float4{0.f, 0.f, 0.f, 0.f};
  *(float4*)jbox[lane] = bj4;
  __syncthreads();
  int i = ib * 64 + lane;
  if (i >= NPRE) return;
  float4 bi = *(const float4*)(sboxes + ((size_t)n * NPRE + i) * 4);
  float ay1 = bi.x, ax1 = bi.y, ay2 = bi.z, ax2 = bi.w;
  float areaA = __fmul_rn(__fsub_rn(ay2, ay1), __fsub_rn(ax2, ax1));
  unsigned long long bits = 0ull;
#pragma unroll 8
  for (int l = 0; l < 64; l++) {
    float4 bj = *(const float4*)jbox[l];
    float ty1 = fmaxf(ay1, bj.x), tx1 = fmaxf(ax1, bj.y);
    float ty2 = fminf(ay2, bj.z), tx2 = fminf(ax2, bj.w);
    float wh0 = fmaxf(__fsub_rn(ty2, ty1), 0.f);
    float wh1 = fmaxf(__fsub_rn(tx2, tx1), 0.f);
    float inter = __fmul_rn(wh0, wh1);
    float areaB = __fmul_rn(__fsub_rn(bj.z, bj.x), __fsub_rn(bj.w, bj.y));
    float den = __fadd_rn(__fsub_rn(__fadd_rn(areaA, areaB), inter), 1e-9f);
    float iou = __fdiv_rn(inter, den);
    if (iou > 0.7f) bits |= (1ull << l);
  }
  mask[((size_t)n * NPRE + i) * 94 + jb] = bits;
}

// =====================================================================
// NMS phase B: sequential greedy reduce, ONE WAVE per batch,
// removed-bitmask lane-distributed in registers, no barriers in loop.
// =====================================================================
__global__ __launch_bounds__(64) void nms_reduce_kernel(
    const unsigned long long* __restrict__ mask,
    const unsigned long long* __restrict__ vmask,
    const float* __restrict__ sboxes, float* __restrict__ out) {
  int n = blockIdx.x;
  int lane = threadIdx.x;
  __shared__ int kept[NPOST];
  __shared__ int s_count;

  // removed init = ~valid  (lane l owns word l and word 64+l)
  unsigned long long rlo = ~vmask[(size_t)n * 94 + lane];
  unsigned long long rhi = (64 + lane < 94) ? ~vmask[(size_t)n * 94 + 64 + lane]
                                            : ~0ull;
  int count = 0;
  for (int c = 0; c < 94 && count < NPOST; c++) {
    unsigned long long curw =
        (c < 64) ? __shfl(rlo, c) : __shfl(rhi, c - 64);
    unsigned long long cand = ~curw;
    while (cand != 0ull && count < NPOST) {
      int b = __builtin_ctzll(cand);
      int i = c * 64 + b;
      if (lane == 0) kept[count] = i;
      count++;
      // OR row i into removed
      const unsigned long long* row = mask + ((size_t)n * NPRE + i) * 94;
      unsigned long long r0 = row[lane];
      unsigned long long r1 = (64 + lane < 94) ? row[64 + lane] : 0ull;
      rlo |= r0; rhi |= r1;
      curw = (c < 64) ? __shfl(rlo, c) : __shfl(rhi, c - 64);
      cand = ~curw;
      cand &= (b == 63) ? 0ull : (~0ull << (b + 1));
    }
  }
  if (lane == 0) s_count = count;
  __syncthreads();
  count = s_count;

  float* rois = out + ROIS_OFF + (size_t)n * NPOST * 4;
  float* ridx = out + RIDX_OFF + (size_t)n * NPOST;
  for (int s = lane; s < NPOST; s += 64) {
    float4 v = {0.f, 0.f, 0.f, 0.f};
    if (s < count) {
      int i = kept[s];
      v = *(const float4*)(sboxes + ((size_t)n * NPRE + i) * 4);
    }
    *(float4*)(rois + (size_t)s * 4) = v;
    ridx[s] = (float)n;
  }
}

// =====================================================================
extern "C" void kernel_launch(void* const* d_in, const int* in_sizes, int n_in,
                              void* d_out, int out_size, void* d_ws,
                              size_t ws_size, hipStream_t stream) {
  const float* feat = (const float*)d_in[0];
  const float* w1 = (const float*)d_in[1];
  const float* b1 = (const float*)d_in[2];
  const float* sw = (const float*)d_in[3];
  const float* sb = (const float*)d_in[4];
  const float* lw = (const float*)d_in[5];
  const float* lb = (const float*)d_in[6];
  const int* pimh = (const int*)d_in[7];
  const int* pimw = (const int*)d_in[8];
  float* out = (float*)d_out;
  char* ws = (char*)d_ws;

  float* wt = (float*)(ws + WT_OFF);
  float* hbuf = (float*)(ws + H_OFF);
  float* boxes = (float*)(ws + BOXES_OFF);
  unsigned long long* keys = (unsigned long long*)(ws + KEYS_OFF);
  unsigned int* hist = (unsigned int*)(ws + HIST_OFF);
  unsigned int* cnts = (unsigned int*)(ws + CNTS_OFF);
  int* scaninfo = (int*)(ws + SCAN_OFF);
  unsigned long long* sel = (unsigned long long*)(ws + SEL_OFF);
  unsigned long long* skeys = (unsigned long long*)(ws + SKEYS_OFF);
  float* sboxes = (float*)(ws + SBOXES_OFF);
  float* wt54 = (float*)(ws + W54_OFF);
  unsigned long long* vmask = (unsigned long long*)(ws + VMASK_OFF);
  unsigned long long* nmask = (unsigned long long*)(ws + MASK_OFF);

  hipMemsetAsync(ws + HIST_OFF, 0, 524288 + 64, stream);
  hipMemsetAsync(ws + SEL_OFF, 0xFF, 122880 + 96000, stream);

  transpose_w_kernel<<<dim3(16, 16), dim3(32, 32), 0, stream>>>(w1, wt);
  transpose54_kernel<<<112, 256, 0, stream>>>(lw, sw, wt54);
  conv1_kernel<<<dim3(128, 8), 256, 0, stream>>>(feat, wt, b1, hbuf);
  heads_kernel<<<2048, 256, 0, stream>>>(hbuf, wt54, lb, sb, out);
  anchors_kernel<<<144, 256, 0, stream>>>(out);
  decode_kernel<<<288, 256, 0, stream>>>(out, pimh, pimw, boxes, keys);
  hist_kernel<<<288, 256, 0, stream>>>(keys, hist);
  scan_kernel<<<1, 1024, 0, stream>>>(hist, scaninfo);
  compact_kernel<<<288, 256, 0, stream>>>(keys, scaninfo, cnts, sel);
  rank_kernel<<<dim3(8, 2), 960, 0, stream>>>(sel, boxes, skeys, sboxes);
  valid_kernel<<<dim3(94, 2), 64, 0, stream>>>(skeys, vmask);
  nms_mask_kernel<<<dim3(94, 94, 2), 64, 0, stream>>>(sboxes, nmask);
  nms_reduce_kernel<<<2, 64, 0, stream>>>(nmask, vmask, sboxes, out);
}

// Round 3
// 1204.567 us; speedup vs baseline: 1.6281x; 1.0615x over previous
//
#include <hip/hip_runtime.h>
#include <cmath>

#define NANCH 36864
#define NPRE 6000
#define NPOST 300
#define SEL_CAP 7680

// ---- output (float) offsets ----
#define LOCS_OFF   0
#define SCORES_OFF 294912
#define ROIS_OFF   442368
#define RIDX_OFF   444768
#define ANCH_OFF   445368

// ---- workspace byte offsets ----
#define WT_OFF      0ull          // 9*512*512*4 = 9437184 (conv1 weights)
#define W54_OFF     0ull          // reuse after conv1: 512*64*4 = 131072
#define MASK_OFF    0ull          // reuse after heads: 2*6000*94*8 = 9024000
#define H_OFF       9437184ull    // 2*512*4096*4  = 16777216
#define BOXES_OFF   26214400ull   // 2*36864*16    = 1179648
#define KEYS_OFF    27394048ull   // 2*36864*8     = 589824
#define HIST_OFF    27983872ull   // 2*65536*4     = 524288
#define CNTS_OFF    28508160ull   // 64
#define SCAN_OFF    28508224ull   // 64
#define SEL_OFF     28508288ull   // 2*7680*8      = 122880
#define SKEYS_OFF   28631168ull   // 2*6000*8      = 96000
#define SBOXES_OFF  28727168ull   // 2*6000*16     = 192000
#define VMASK_OFF   29033856ull   // 2*94*8        = 1504

__device__ __forceinline__ void load_lds16(const float* g, float* l) {
#if __has_builtin(__builtin_amdgcn_global_load_lds)
  __builtin_amdgcn_global_load_lds(
      (const __attribute__((address_space(1))) void*)g,
      (__attribute__((address_space(3))) void*)l, 16, 0, 0);
#else
  // fallback: per-lane vector load + LDS write (lane offset handled by caller
  // pattern: dest base + lane*16 — emulate)
  int lane = threadIdx.x & 63;
  float4 v = *(const float4*)g;
  *(float4*)((char*)l + lane * 16) = v;
#endif
}

// =====================================================================
// Weight transpose: w[co][ci][kk] -> wt[kk][ci][co]
// =====================================================================
__global__ __launch_bounds__(1024) void transpose_w_kernel(
    const float* __restrict__ w, float* __restrict__ wt) {
  __shared__ float lds[9][32][33];
  int tx = threadIdx.x;
  int ty = threadIdx.y;
  int ci0 = blockIdx.x * 32;
  int co0 = blockIdx.y * 32;
  const float* src = w + ((size_t)(co0 + ty) * 512 + (ci0 + tx)) * 9;
#pragma unroll
  for (int k = 0; k < 9; k++) lds[k][tx][ty] = src[k];
  __syncthreads();
#pragma unroll
  for (int k = 0; k < 9; k++) {
    wt[((size_t)k * 512 + (ci0 + ty)) * 512 + co0 + tx] = lds[k][ty][tx];
  }
}

// =====================================================================
// 1x1 head weights -> w54p[512][64] (cols 54..63 zero)
// =====================================================================
__global__ void transpose54_kernel(const float* __restrict__ lw,
                                   const float* __restrict__ sw,
                                   float* __restrict__ wt) {
  int t = blockIdx.x * 256 + threadIdx.x;   // < 32768
  int k = t >> 6, co = t & 63;
  float v = 0.f;
  if (co < 36) v = lw[(size_t)co * 512 + k];
  else if (co < 54) v = sw[(size_t)(co - 36) * 512 + k];
  wt[t] = v;
}

// =====================================================================
// conv1 v2: 3x3 512->512 pad1 + bias + ReLU.  Halo-staged implicit GEMM.
// Block = 64 x (one y row) x 128 co; 256 thr; micro 4x8.
// grid.x = n*64+y (128), grid.y = co/128 (4) -> 512 blocks = 2/CU.
// LDS: As[8ci][3yr][72] (cols 4..67 = x[0..63], pads zero) + Bs[9kk][8ci][128]
// =====================================================================
__global__ __launch_bounds__(256) void conv1_kernel(
    const float* __restrict__ x, const float* __restrict__ wt,
    const float* __restrict__ bias, float* __restrict__ hout) {
  __shared__ __align__(16) float As[24 * 72];
  __shared__ __align__(16) float Bs[72 * 128];
  int mb = blockIdx.x;
  int n = mb >> 6, y = mb & 63;
  int co0 = blockIdx.y << 7;
  int tid = threadIdx.x;
  int tx = tid & 15, ty = tid >> 4;
  int x0 = tx << 2;

  float acc[8][4];
#pragma unroll
  for (int j = 0; j < 8; j++)
#pragma unroll
    for (int i = 0; i < 4; i++) acc[j][i] = 0.f;

  const float* xb = x + (size_t)n * 512 * 4096;

  // zero the As pads once (cols 0..3, 68..71 of all 24 rows); stays zero.
  if (tid < 192) {
    int row = tid >> 3, c = tid & 7;
    int col = (c < 4) ? c : (64 + c);
    As[row * 72 + col] = 0.f;
  }

  int wv = tid >> 6;
  int lane = tid & 63;
  int rsub = lane >> 5;
  int bcol = (lane & 31) << 2;

  for (int ci0 = 0; ci0 < 512; ci0 += 8) {
    // ---- stage A: 24 rows (8 ci x 3 yr) x 64 floats ----
    for (int t = tid; t < 384; t += 256) {
      int row = t >> 4;          // ci*3+yr
      int l = t & 15;
      int ci = row / 3;
      int yr = row - ci * 3;
      int ys = y + yr - 1;
      float4 v = {0.f, 0.f, 0.f, 0.f};
      if (ys >= 0 && ys < 64)
        v = *(const float4*)&xb[(((size_t)(ci0 + ci)) << 12) + (ys << 6) + (l << 2)];
      *(float4*)&As[row * 72 + 4 + (l << 2)] = v;
    }
    // ---- stage B: 72 rows (kk*8+ci) x 128 co via global_load_lds ----
    for (int i = 0; i < 9; i++) {
      int row0 = i * 8 + wv * 2;
      int row = row0 + rsub;
      int kk = row >> 3, ci = row & 7;
      const float* g = wt + (((size_t)kk << 9) + ci0 + ci) * 512 + co0 + bcol;
      load_lds16(g, &Bs[row0 << 7]);
    }
    __syncthreads();
    // ---- compute: 8 ci x 9 taps x 32 fma ----
    for (int k = 0; k < 8; k++) {
      const float* ar = &As[k * 3 * 72];
#pragma unroll
      for (int ky = 0; ky < 3; ky++) {
        const float* arr = ar + ky * 72;
        float4 a4 = *(const float4*)&arr[x0 + 4];
        float w[6];
        w[0] = arr[x0 + 3];
        w[1] = a4.x; w[2] = a4.y; w[3] = a4.z; w[4] = a4.w;
        w[5] = arr[x0 + 8];
#pragma unroll
        for (int kx = 0; kx < 3; kx++) {
          int kk = ky * 3 + kx;
          const float* br = &Bs[(((kk << 3) + k) << 7) + (ty << 3)];
          float4 b0 = *(const float4*)br;
          float4 b1 = *(const float4*)(br + 4);
          float bb[8] = {b0.x, b0.y, b0.z, b0.w, b1.x, b1.y, b1.z, b1.w};
#pragma unroll
          for (int j = 0; j < 8; j++)
#pragma unroll
            for (int dx = 0; dx < 4; dx++)
              acc[j][dx] = fmaf(w[kx + dx], bb[j], acc[j][dx]);
        }
      }
    }
    __syncthreads();
  }
  // ---- epilogue ----
#pragma unroll
  for (int j = 0; j < 8; j++) {
    int co = co0 + (ty << 3) + j;
    float bv = bias[co];
    float4 v;
    v.x = fmaxf(acc[j][0] + bv, 0.f);
    v.y = fmaxf(acc[j][1] + bv, 0.f);
    v.z = fmaxf(acc[j][2] + bv, 0.f);
    v.w = fmaxf(acc[j][3] + bv, 0.f);
    *(float4*)&hout[(((size_t)(n * 512 + co)) << 12) + (y << 6) + x0] = v;
  }
}

// =====================================================================
// heads v2: tiled GEMM  M=64 p x N=54 co x K=512.
// Same ascending-k fma chain per (p,co) as R2 -> bit-identical outputs.
// grid = 128 blocks (2n x 64 ptiles), 256 thr.
// =====================================================================
__global__ __launch_bounds__(256) void heads_kernel(
    const float* __restrict__ h, const float* __restrict__ w54p,
    const float* __restrict__ loc_b, const float* __restrict__ score_b,
    float* __restrict__ out) {
  __shared__ __align__(16) float hs[32 * 64];
  __shared__ __align__(16) float wsd[32 * 64];
  __shared__ float sacc[64 * 65];
  int n = blockIdx.x >> 6;
  int p0 = (blockIdx.x & 63) << 6;
  int tid = threadIdx.x;
  int txp = tid & 63;
  int tw = tid >> 6;
  float acc[16];
#pragma unroll
  for (int j = 0; j < 16; j++) acc[j] = 0.f;
  const float* hb = h + ((size_t)n * 512) * 4096 + p0;
  for (int k0 = 0; k0 < 512; k0 += 32) {
    for (int t = tid; t < 512; t += 256) {
      int r = t >> 4, l = (t & 15) << 2;
      *(float4*)&hs[(r << 6) + l] =
          *(const float4*)&hb[(((size_t)(k0 + r)) << 12) + l];
      *(float4*)&wsd[(r << 6) + l] =
          *(const float4*)&w54p[((k0 + r) << 6) + l];
    }
    __syncthreads();
    for (int k = 0; k < 32; k++) {
      float hv = hs[(k << 6) + txp];
      const float* wr = &wsd[(k << 6) + (tw << 4)];
#pragma unroll
      for (int u = 0; u < 4; u++) {
        float4 wv = *(const float4*)(wr + (u << 2));
        acc[u * 4 + 0] = fmaf(hv, wv.x, acc[u * 4 + 0]);
        acc[u * 4 + 1] = fmaf(hv, wv.y, acc[u * 4 + 1]);
        acc[u * 4 + 2] = fmaf(hv, wv.z, acc[u * 4 + 2]);
        acc[u * 4 + 3] = fmaf(hv, wv.w, acc[u * 4 + 3]);
      }
    }
    __syncthreads();
  }
#pragma unroll
  for (int j = 0; j < 16; j++) sacc[(tw * 16 + j) * 65 + txp] = acc[j];
  __syncthreads();
  for (int t = tid; t < 64 * 54; t += 256) {
    int p = t / 54, c = t - p * 54;
    float v = sacc[c * 65 + p];
    int gp = (n << 12) + p0 + p;
    if (c < 36) out[LOCS_OFF + (size_t)gp * 36 + c] = v + loc_b[c];
    else out[SCORES_OFF + (size_t)gp * 18 + (c - 36)] = v + score_b[c - 36];
  }
}

// =====================================================================
// Anchors (fp64 base rounded once to fp32, matching np)
// =====================================================================
__global__ void anchors_kernel(float* __restrict__ out) {
  int k = blockIdx.x * 256 + threadIdx.x;
  int a = k % 9, pos = k / 9;
  int j = pos & 63, i = pos >> 6;
  int ridx = a / 3, sidx = a % 3;
  double r = (ridx == 0) ? 0.5 : ((ridx == 1) ? 1.0 : 2.0);
  double s = (sidx == 0) ? 8.0 : ((sidx == 1) ? 16.0 : 32.0);
  double hh = 16.0 * s * sqrt(r);
  double ww = 16.0 * s * sqrt(1.0 / r);
  float b0 = (float)(8.0 - hh / 2.0), b1 = (float)(8.0 - ww / 2.0);
  float b2 = (float)(8.0 + hh / 2.0), b3 = (float)(8.0 + ww / 2.0);
  float sy = (float)(i * 16), sx = (float)(j * 16);
  float* o = out + ANCH_OFF + (size_t)k * 4;
  o[0] = sy + b0; o[1] = sx + b1; o[2] = sy + b2; o[3] = sx + b3;
}

// =====================================================================
// Decode: boxes + clip + valid + fg score + sortable key
// =====================================================================
__global__ void decode_kernel(const float* __restrict__ out,
                              const int* __restrict__ pimh,
                              const int* __restrict__ pimw,
                              float* __restrict__ boxes,
                              unsigned long long* __restrict__ keys) {
  int t = blockIdx.x * 256 + threadIdx.x;
  int n = t / NANCH, k = t - n * NANCH;
  float imh = (float)pimh[0], imw = (float)pimw[0];
  const float* an = out + ANCH_OFF + (size_t)k * 4;
  const float* loc = out + LOCS_OFF + (size_t)t * 4;
  const float* sc = out + SCORES_OFF + (size_t)t * 2;
  float a0 = an[0], a1 = an[1], a2 = an[2], a3 = an[3];
  float ah = __fsub_rn(a2, a0), aw = __fsub_rn(a3, a1);
  float acy = __fadd_rn(a0, 0.5f * ah), acx = __fadd_rn(a1, 0.5f * aw);
  float dy = loc[0], dx = loc[1], dh = loc[2], dw = loc[3];
  float cy = __fadd_rn(__fmul_rn(dy, ah), acy);
  float cx = __fadd_rn(__fmul_rn(dx, aw), acx);
  float hh = __fmul_rn(expf(dh), ah);
  float ww = __fmul_rn(expf(dw), aw);
  float y1 = __fsub_rn(cy, 0.5f * hh), x1 = __fsub_rn(cx, 0.5f * ww);
  float y2 = __fadd_rn(cy, 0.5f * hh), x2 = __fadd_rn(cx, 0.5f * ww);
  y1 = fminf(fmaxf(y1, 0.f), imh); x1 = fminf(fmaxf(x1, 0.f), imw);
  y2 = fminf(fmaxf(y2, 0.f), imh); x2 = fminf(fmaxf(x2, 0.f), imw);
  bool valid = (__fsub_rn(y2, y1) >= 16.f) && (__fsub_rn(x2, x1) >= 16.f);
  float s0 = sc[0], s1 = sc[1];
  float m = fmaxf(s0, s1);
  float e0 = expf(__fsub_rn(s0, m)), e1 = expf(__fsub_rn(s1, m));
  float fg = __fdiv_rn(e1, __fadd_rn(e0, e1));
  float score = valid ? fg : -INFINITY;
  unsigned int u = __float_as_uint(score);
  unsigned int ord = (u & 0x80000000u) ? ~u : (u | 0x80000000u);
  unsigned long long key =
      ((unsigned long long)(~ord) << 16) | (unsigned long long)(k & 0xFFFF);
  float4 b4; b4.x = y1; b4.y = x1; b4.z = y2; b4.w = x2;
  *(float4*)(boxes + (size_t)t * 4) = b4;
  keys[t] = key;
}

// =====================================================================
// Histogram on top-16 key bits (per batch)
// =====================================================================
__global__ void hist_kernel(const unsigned long long* __restrict__ keys,
                            unsigned int* __restrict__ hist) {
  int t = blockIdx.x * 256 + threadIdx.x;
  int n = t / NANCH;
  unsigned int b = (unsigned int)(keys[t] >> 32);
  atomicAdd(&hist[(size_t)n * 65536 + b], 1u);
}

// =====================================================================
// Scan: find cutoff bucket b* per batch
// =====================================================================
__global__ __launch_bounds__(1024) void scan_kernel(
    const unsigned int* __restrict__ hist, int* __restrict__ scaninfo) {
  __shared__ unsigned int ps[1024];
  int tid = threadIdx.x;
  for (int n = 0; n < 2; n++) {
    const unsigned int* h = hist + (size_t)n * 65536;
    int base = tid * 64;
    unsigned int s = 0;
    for (int i = 0; i < 64; i++) s += h[base + i];
    ps[tid] = s;
    __syncthreads();
    for (int off = 1; off < 1024; off <<= 1) {
      unsigned int v = ps[tid];
      unsigned int add = (tid >= off) ? ps[tid - off] : 0u;
      __syncthreads();
      ps[tid] = v + add;
      __syncthreads();
    }
    unsigned int incl = ps[tid];
    unsigned int excl = incl - s;
    if (excl < (unsigned)NPRE && incl >= (unsigned)NPRE) {
      unsigned int c = excl;
      for (int i = 0; i < 64; i++) {
        unsigned int hv = h[base + i];
        if (c + hv >= (unsigned)NPRE) {
          scaninfo[n * 2] = base + i;
          scaninfo[n * 2 + 1] = (int)c;
          break;
        }
        c += hv;
      }
    }
    __syncthreads();
  }
}

// =====================================================================
// Compact
// =====================================================================
__global__ void compact_kernel(const unsigned long long* __restrict__ keys,
                               const int* __restrict__ scaninfo,
                               unsigned int* __restrict__ cnts,
                               unsigned long long* __restrict__ sel) {
  int t = blockIdx.x * 256 + threadIdx.x;
  int n = t / NANCH;
  unsigned long long key = keys[t];
  int b = (int)(unsigned int)(key >> 32);
  int bstar = scaninfo[n * 2];
  if (b < bstar) {
    unsigned int p = atomicAdd(&cnts[n * 2], 1u);
    sel[(size_t)n * SEL_CAP + p] = key;
  } else if (b == bstar) {
    unsigned int p = (unsigned)NPRE + atomicAdd(&cnts[n * 2 + 1], 1u);
    if (p < (unsigned)SEL_CAP) sel[(size_t)n * SEL_CAP + p] = key;
  }
}

// =====================================================================
// Rank: exact global rank by counting
// =====================================================================
__global__ __launch_bounds__(960) void rank_kernel(
    const unsigned long long* __restrict__ sel,
    const float* __restrict__ boxes,
    unsigned long long* __restrict__ skeys, float* __restrict__ sboxes) {
  int n = blockIdx.y;
  const unsigned long long* s = sel + (size_t)n * SEL_CAP;
  __shared__ unsigned long long lds[SEL_CAP];
  int tid = threadIdx.x;
  for (int i = tid; i < SEL_CAP; i += 960) lds[i] = s[i];
  __syncthreads();
  int e = blockIdx.x * 960 + tid;
  unsigned long long my = lds[e];
  int r = 0;
#pragma unroll 8
  for (int j = 0; j < SEL_CAP; j++) r += (lds[j] < my) ? 1 : 0;
  if (r < NPRE) {
    skeys[(size_t)n * NPRE + r] = my;
    unsigned int hi = (unsigned int)(my >> 16);
    if (hi < 0xFF800000u) {
      int k = (int)(my & 0xFFFFull);
      float4 bx = *(const float4*)(boxes + ((size_t)n * NANCH + k) * 4);
      *(float4*)(sboxes + ((size_t)n * NPRE + r) * 4) = bx;
    }
  }
}

// =====================================================================
// Validity bitmask of the 6000 sorted slots: vmask[n][94]
// =====================================================================
__global__ void valid_kernel(const unsigned long long* __restrict__ skeys,
                             unsigned long long* __restrict__ vmask) {
  int n = blockIdx.y;
  int w = blockIdx.x;
  int lane = threadIdx.x;
  int j = w * 64 + lane;
  bool ok = false;
  if (j < NPRE) {
    unsigned int hi = (unsigned int)(skeys[(size_t)n * NPRE + j] >> 16);
    ok = hi < 0xFF800000u;
  }
  unsigned long long m = __ballot(ok);
  if (lane == 0) vmask[(size_t)n * 94 + w] = m;
}

// =====================================================================
// NMS phase A: pairwise suppression bitmask
// =====================================================================
__global__ __launch_bounds__(64) void nms_mask_kernel(
    const float* __restrict__ sboxes, unsigned long long* __restrict__ mask) {
  int n = blockIdx.z;
  int ib = blockIdx.x, jb = blockIdx.y;
  int lane = threadIdx.x;
  __shared__ __align__(16) float jbox[64][4];
  int j = jb * 64 + lane;
  float4 bj4 = (j < NPRE)
                   ? *(const float4*)(sboxes + ((size_t)n * NPRE + j) * 4)
                   : float4{0.f, 0.f, 0.f, 0.f};
  *(float4*)jbox[lane] = bj4;
  __syncthreads();
  int i = ib * 64 + lane;
  if (i >= NPRE) return;
  float4 bi = *(const float4*)(sboxes + ((size_t)n * NPRE + i) * 4);
  float ay1 = bi.x, ax1 = bi.y, ay2 = bi.z, ax2 = bi.w;
  float areaA = __fmul_rn(__fsub_rn(ay2, ay1), __fsub_rn(ax2, ax1));
  unsigned long long bits = 0ull;
#pragma unroll 8
  for (int l = 0; l < 64; l++) {
    float4 bj = *(const float4*)jbox[l];
    float ty1 = fmaxf(ay1, bj.x), tx1 = fmaxf(ax1, bj.y);
    float ty2 = fminf(ay2, bj.z), tx2 = fminf(ax2, bj.w);
    float wh0 = fmaxf(__fsub_rn(ty2, ty1), 0.f);
    float wh1 = fmaxf(__fsub_rn(tx2, tx1), 0.f);
    float inter = __fmul_rn(wh0, wh1);
    float areaB = __fmul_rn(__fsub_rn(bj.z, bj.x), __fsub_rn(bj.w, bj.y));
    float den = __fadd_rn(__fsub_rn(__fadd_rn(areaA, areaB), inter), 1e-9f);
    float iou = __fdiv_rn(inter, den);
    if (iou > 0.7f) bits |= (1ull << l);
  }
  mask[((size_t)n * NPRE + i) * 94 + jb] = bits;
}

// =====================================================================
// NMS phase B: sequential greedy reduce, one wave per batch
// =====================================================================
__global__ __launch_bounds__(64) void nms_reduce_kernel(
    const unsigned long long* __restrict__ mask,
    const unsigned long long* __restrict__ vmask,
    const float* __restrict__ sboxes, float* __restrict__ out) {
  int n = blockIdx.x;
  int lane = threadIdx.x;
  __shared__ int kept[NPOST];
  __shared__ int s_count;

  unsigned long long rlo = ~vmask[(size_t)n * 94 + lane];
  unsigned long long rhi = (64 + lane < 94) ? ~vmask[(size_t)n * 94 + 64 + lane]
                                            : ~0ull;
  int count = 0;
  for (int c = 0; c < 94 && count < NPOST; c++) {
    unsigned long long curw =
        (c < 64) ? __shfl(rlo, c) : __shfl(rhi, c - 64);
    unsigned long long cand = ~curw;
    while (cand != 0ull && count < NPOST) {
      int b = __builtin_ctzll(cand);
      int i = c * 64 + b;
      if (lane == 0) kept[count] = i;
      count++;
      const unsigned long long* row = mask + ((size_t)n * NPRE + i) * 94;
      unsigned long long r0 = row[lane];
      unsigned long long r1 = (64 + lane < 94) ? row[64 + lane] : 0ull;
      rlo |= r0; rhi |= r1;
      curw = (c < 64) ? __shfl(rlo, c) : __shfl(rhi, c - 64);
      cand = ~curw;
      cand &= (b == 63) ? 0ull : (~0ull << (b + 1));
    }
  }
  if (lane == 0) s_count = count;
  __syncthreads();
  count = s_count;

  float* rois = out + ROIS_OFF + (size_t)n * NPOST * 4;
  float* ridx = out + RIDX_OFF + (size_t)n * NPOST;
  for (int s = lane; s < NPOST; s += 64) {
    float4 v = {0.f, 0.f, 0.f, 0.f};
    if (s < count) {
      int i = kept[s];
      v = *(const float4*)(sboxes + ((size_t)n * NPRE + i) * 4);
    }
    *(float4*)(rois + (size_t)s * 4) = v;
    ridx[s] = (float)n;
  }
}

// =====================================================================
extern "C" void kernel_launch(void* const* d_in, const int* in_sizes, int n_in,
                              void* d_out, int out_size, void* d_ws,
                              size_t ws_size, hipStream_t stream) {
  const float* feat = (const float*)d_in[0];
  const float* w1 = (const float*)d_in[1];
  const float* b1 = (const float*)d_in[2];
  const float* sw = (const float*)d_in[3];
  const float* sb = (const float*)d_in[4];
  const float* lw = (const float*)d_in[5];
  const float* lb = (const float*)d_in[6];
  const int* pimh = (const int*)d_in[7];
  const int* pimw = (const int*)d_in[8];
  float* out = (float*)d_out;
  char* ws = (char*)d_ws;

  float* wt = (float*)(ws + WT_OFF);
  float* w54p = (float*)(ws + W54_OFF);
  float* hbuf = (float*)(ws + H_OFF);
  float* boxes = (float*)(ws + BOXES_OFF);
  unsigned long long* keys = (unsigned long long*)(ws + KEYS_OFF);
  unsigned int* hist = (unsigned int*)(ws + HIST_OFF);
  unsigned int* cnts = (unsigned int*)(ws + CNTS_OFF);
  int* scaninfo = (int*)(ws + SCAN_OFF);
  unsigned long long* sel = (unsigned long long*)(ws + SEL_OFF);
  unsigned long long* skeys = (unsigned long long*)(ws + SKEYS_OFF);
  float* sboxes = (float*)(ws + SBOXES_OFF);
  unsigned long long* vmask = (unsigned long long*)(ws + VMASK_OFF);
  unsigned long long* nmask = (unsigned long long*)(ws + MASK_OFF);

  hipMemsetAsync(ws + HIST_OFF, 0, 524288 + 64, stream);
  hipMemsetAsync(ws + SEL_OFF, 0xFF, 122880 + 96000, stream);

  transpose_w_kernel<<<dim3(16, 16), dim3(32, 32), 0, stream>>>(w1, wt);
  conv1_kernel<<<dim3(128, 4), 256, 0, stream>>>(feat, wt, b1, hbuf);
  // wt dead; w54p overwrites it (same offset 0)
  transpose54_kernel<<<128, 256, 0, stream>>>(lw, sw, w54p);
  heads_kernel<<<128, 256, 0, stream>>>(hbuf, w54p, lb, sb, out);
  anchors_kernel<<<144, 256, 0, stream>>>(out);
  decode_kernel<<<288, 256, 0, stream>>>(out, pimh, pimw, boxes, keys);
  hist_kernel<<<288, 256, 0, stream>>>(keys, hist);
  scan_kernel<<<1, 1024, 0, stream>>>(hist, scaninfo);
  compact_kernel<<<288, 256, 0, stream>>>(keys, scaninfo, cnts, sel);
  rank_kernel<<<dim3(8, 2), 960, 0, stream>>>(sel, boxes, skeys, sboxes);
  valid_kernel<<<dim3(94, 2), 64, 0, stream>>>(skeys, vmask);
  // w54p dead; nmask overwrites it (same offset 0)
  nms_mask_kernel<<<dim3(94, 94, 2), 64, 0, stream>>>(sboxes, nmask);
  nms_reduce_kernel<<<2, 64, 0, stream>>>(nmask, vmask, sboxes, out);
}

// Round 4
// 1100.259 us; speedup vs baseline: 1.7825x; 1.0948x over previous
//
#include <hip/hip_runtime.h>
#include <cmath>

#define NANCH 36864
#define NPRE 6000
#define NPOST 300

// ---- output (float) offsets ----
#define LOCS_OFF   0
#define SCORES_OFF 294912
#define ROIS_OFF   442368
#define RIDX_OFF   444768
#define ANCH_OFF   445368

// ---- workspace byte offsets ----
#define WT_OFF      0ull          // 9*512*512*4 = 9437184 (conv1 weights)
#define W54_OFF     0ull          // reuse after conv1: 512*64*4 = 131072
#define PREFIX_OFF  2097152ull    // 2*65536*4 = 524288 (inside dead WT region)
#define PREFIXM_OFF 2621440ull    // 2*65536*4 = 524288
#define SORTED_OFF  3145728ull    // 2*8192*8  = 131072
#define MASK_OFF    0ull          // reuse after fixup: 2*6000*94*8 = 9024000
#define H_OFF       9437184ull    // 2*512*4096*4  = 16777216
#define BOXES_OFF   26214400ull   // 2*36864*16    = 1179648
#define KEYS_OFF    27394048ull   // 2*36864*8     = 589824
#define HIST_OFF    27983872ull   // 2*65536*4     = 524288
#define SKEYS_OFF   28631168ull   // 2*6000*8      = 96000
#define SBOXES_OFF  28727168ull   // 2*6000*16     = 192000
#define VMASK_OFF   29033856ull   // 2*94*8        = 1504

__device__ __forceinline__ void load_lds16(const float* g, float* l) {
#if __has_builtin(__builtin_amdgcn_global_load_lds)
  __builtin_amdgcn_global_load_lds(
      (const __attribute__((address_space(1))) void*)g,
      (__attribute__((address_space(3))) void*)l, 16, 0, 0);
#else
  int lane = threadIdx.x & 63;
  float4 v = *(const float4*)g;
  *(float4*)((char*)l + lane * 16) = v;
#endif
}

// =====================================================================
// Weight transpose: w[co][ci][kk] -> wt[kk][ci][co]
// =====================================================================
__global__ __launch_bounds__(1024) void transpose_w_kernel(
    const float* __restrict__ w, float* __restrict__ wt) {
  __shared__ float lds[9][32][33];
  int tx = threadIdx.x;
  int ty = threadIdx.y;
  int ci0 = blockIdx.x * 32;
  int co0 = blockIdx.y * 32;
  const float* src = w + ((size_t)(co0 + ty) * 512 + (ci0 + tx)) * 9;
#pragma unroll
  for (int k = 0; k < 9; k++) lds[k][tx][ty] = src[k];
  __syncthreads();
#pragma unroll
  for (int k = 0; k < 9; k++) {
    wt[((size_t)k * 512 + (ci0 + ty)) * 512 + co0 + tx] = lds[k][ty][tx];
  }
}

// =====================================================================
// 1x1 head weights -> w54p[512][64] (cols 54..63 zero)
// =====================================================================
__global__ void transpose54_kernel(const float* __restrict__ lw,
                                   const float* __restrict__ sw,
                                   float* __restrict__ wt) {
  int t = blockIdx.x * 256 + threadIdx.x;   // < 32768
  int k = t >> 6, co = t & 63;
  float v = 0.f;
  if (co < 36) v = lw[(size_t)co * 512 + k];
  else if (co < 54) v = sw[(size_t)(co - 36) * 512 + k];
  wt[t] = v;
}

// =====================================================================
// conv1 v3: 3x3 512->512 pad1 + bias + ReLU.
// 128 thr (2 waves), tile 64x x 128co, micro-tile 8x x 8co (64 acc).
// grid.x = n*64+y (128), grid.y = co/128 (4) -> 512 blocks.
// LDS 43.8 KB: As[24][72] halo rows + Bs[72][128].
// Per ci: 408 B LDS / 576 fma = 0.71 B/fma -> fma-bound.
// Accumulation order (ci asc, ky, kx) identical to R3 -> bit-identical h.
// =====================================================================
__global__ __launch_bounds__(128) void conv1_kernel(
    const float* __restrict__ x, const float* __restrict__ wt,
    const float* __restrict__ bias, float* __restrict__ hout) {
  __shared__ __align__(16) float As[24 * 72];
  __shared__ __align__(16) float Bs[72 * 128];
  int mb = blockIdx.x;
  int n = mb >> 6, y = mb & 63;
  int co0 = blockIdx.y << 7;
  int tid = threadIdx.x;
  int tx = tid & 7, ty = tid >> 3;   // tx: x-group, ty: co-group (0..15)
  int x0 = tx << 3;

  float acc[8][8];                   // [co j][x dx]
#pragma unroll
  for (int j = 0; j < 8; j++)
#pragma unroll
    for (int i = 0; i < 8; i++) acc[j][i] = 0.f;

  const float* xb = x + ((size_t)n << 21);

  // zero the As pads (cols 0..3, 68..71 of 24 rows); stays zero.
  for (int t = tid; t < 192; t += 128) {
    int row = t >> 3, c = t & 7;
    int col = (c < 4) ? c : (64 + c);
    As[row * 72 + col] = 0.f;
  }

  int wv = tid >> 6;
  int lane = tid & 63;
  int lrow = lane >> 5;
  int lcol = (lane & 31) << 2;

  for (int ci0 = 0; ci0 < 512; ci0 += 8) {
    // ---- stage A: 24 rows (8 ci x 3 yr) x 64 floats; 3 float4/thread ----
    for (int t = tid; t < 384; t += 128) {
      int row = t >> 4;
      int l = t & 15;
      int ci = row / 3;
      int yr = row - ci * 3;
      int ys = y + yr - 1;
      float4 v = {0.f, 0.f, 0.f, 0.f};
      if (ys >= 0 && ys < 64)
        v = *(const float4*)&xb[(((size_t)(ci0 + ci)) << 12) + (ys << 6) + (l << 2)];
      *(float4*)&As[row * 72 + 4 + (l << 2)] = v;
    }
    // ---- stage B: 72 rows x 128 co; 18 global_load_lds per wave ----
    for (int i = 0; i < 18; i++) {
      int r0 = i * 4 + wv * 2;
      int row = r0 + lrow;
      int kk = row >> 3, ci = row & 7;
      const float* g = wt + (((size_t)(kk << 9)) + ci0 + ci) * 512 + co0 + lcol;
      load_lds16(g, &Bs[r0 << 7]);
    }
    __syncthreads();
    // ---- compute: 8 ci x 3 ky x 3 kx x 64 fma ----
    for (int k = 0; k < 8; k++) {
      const float* ar = &As[k * 216];
#pragma unroll
      for (int ky = 0; ky < 3; ky++) {
        const float* arr = ar + ky * 72;
        float w10[10];
        w10[0] = arr[x0 + 3];
        float4 a0 = *(const float4*)&arr[x0 + 4];
        float4 a1 = *(const float4*)&arr[x0 + 8];
        w10[1] = a0.x; w10[2] = a0.y; w10[3] = a0.z; w10[4] = a0.w;
        w10[5] = a1.x; w10[6] = a1.y; w10[7] = a1.z; w10[8] = a1.w;
        w10[9] = arr[x0 + 12];
#pragma unroll
        for (int kx = 0; kx < 3; kx++) {
          int kk = ky * 3 + kx;
          const float* br = &Bs[(((kk << 3) + k) << 7) + (ty << 3)];
          float4 b0 = *(const float4*)br;
          float4 b1 = *(const float4*)(br + 4);
          float bb[8] = {b0.x, b0.y, b0.z, b0.w, b1.x, b1.y, b1.z, b1.w};
#pragma unroll
          for (int j = 0; j < 8; j++)
#pragma unroll
            for (int dx = 0; dx < 8; dx++)
              acc[j][dx] = fmaf(w10[kx + dx], bb[j], acc[j][dx]);
        }
      }
    }
    __syncthreads();
  }
  // ---- epilogue ----
#pragma unroll
  for (int j = 0; j < 8; j++) {
    int co = co0 + (ty << 3) + j;
    float bv = bias[co];
    float4 v0, v1;
    v0.x = fmaxf(acc[j][0] + bv, 0.f);
    v0.y = fmaxf(acc[j][1] + bv, 0.f);
    v0.z = fmaxf(acc[j][2] + bv, 0.f);
    v0.w = fmaxf(acc[j][3] + bv, 0.f);
    v1.x = fmaxf(acc[j][4] + bv, 0.f);
    v1.y = fmaxf(acc[j][5] + bv, 0.f);
    v1.z = fmaxf(acc[j][6] + bv, 0.f);
    v1.w = fmaxf(acc[j][7] + bv, 0.f);
    float* o = &hout[(((size_t)(n * 512 + co)) << 12) + (y << 6) + x0];
    *(float4*)o = v0;
    *(float4*)(o + 4) = v1;
  }
}

// =====================================================================
// heads: tiled GEMM M=64p x N=54 x K=512 (unchanged, bit-identical)
// =====================================================================
__global__ __launch_bounds__(256) void heads_kernel(
    const float* __restrict__ h, const float* __restrict__ w54p,
    const float* __restrict__ loc_b, const float* __restrict__ score_b,
    float* __restrict__ out) {
  __shared__ __align__(16) float hs[32 * 64];
  __shared__ __align__(16) float wsd[32 * 64];
  __shared__ float sacc[64 * 65];
  int n = blockIdx.x >> 6;
  int p0 = (blockIdx.x & 63) << 6;
  int tid = threadIdx.x;
  int txp = tid & 63;
  int tw = tid >> 6;
  float acc[16];
#pragma unroll
  for (int j = 0; j < 16; j++) acc[j] = 0.f;
  const float* hb = h + ((size_t)n * 512) * 4096 + p0;
  for (int k0 = 0; k0 < 512; k0 += 32) {
    for (int t = tid; t < 512; t += 256) {
      int r = t >> 4, l = (t & 15) << 2;
      *(float4*)&hs[(r << 6) + l] =
          *(const float4*)&hb[(((size_t)(k0 + r)) << 12) + l];
      *(float4*)&wsd[(r << 6) + l] =
          *(const float4*)&w54p[((k0 + r) << 6) + l];
    }
    __syncthreads();
    for (int k = 0; k < 32; k++) {
      float hv = hs[(k << 6) + txp];
      const float* wr = &wsd[(k << 6) + (tw << 4)];
#pragma unroll
      for (int u = 0; u < 4; u++) {
        float4 wv = *(const float4*)(wr + (u << 2));
        acc[u * 4 + 0] = fmaf(hv, wv.x, acc[u * 4 + 0]);
        acc[u * 4 + 1] = fmaf(hv, wv.y, acc[u * 4 + 1]);
        acc[u * 4 + 2] = fmaf(hv, wv.z, acc[u * 4 + 2]);
        acc[u * 4 + 3] = fmaf(hv, wv.w, acc[u * 4 + 3]);
      }
    }
    __syncthreads();
  }
#pragma unroll
  for (int j = 0; j < 16; j++) sacc[(tw * 16 + j) * 65 + txp] = acc[j];
  __syncthreads();
  for (int t = tid; t < 64 * 54; t += 256) {
    int p = t / 54, c = t - p * 54;
    float v = sacc[c * 65 + p];
    int gp = (n << 12) + p0 + p;
    if (c < 36) out[LOCS_OFF + (size_t)gp * 36 + c] = v + loc_b[c];
    else out[SCORES_OFF + (size_t)gp * 18 + (c - 36)] = v + score_b[c - 36];
  }
}

// =====================================================================
// Anchors
// =====================================================================
__global__ void anchors_kernel(float* __restrict__ out) {
  int k = blockIdx.x * 256 + threadIdx.x;
  int a = k % 9, pos = k / 9;
  int j = pos & 63, i = pos >> 6;
  int ridx = a / 3, sidx = a % 3;
  double r = (ridx == 0) ? 0.5 : ((ridx == 1) ? 1.0 : 2.0);
  double s = (sidx == 0) ? 8.0 : ((sidx == 1) ? 16.0 : 32.0);
  double hh = 16.0 * s * sqrt(r);
  double ww = 16.0 * s * sqrt(1.0 / r);
  float b0 = (float)(8.0 - hh / 2.0), b1 = (float)(8.0 - ww / 2.0);
  float b2 = (float)(8.0 + hh / 2.0), b3 = (float)(8.0 + ww / 2.0);
  float sy = (float)(i * 16), sx = (float)(j * 16);
  float* o = out + ANCH_OFF + (size_t)k * 4;
  o[0] = sy + b0; o[1] = sx + b1; o[2] = sy + b2; o[3] = sx + b3;
}

// =====================================================================
// Decode: boxes + clip + valid + fg score + sortable key
// =====================================================================
__global__ void decode_kernel(const float* __restrict__ out,
                              const int* __restrict__ pimh,
                              const int* __restrict__ pimw,
                              float* __restrict__ boxes,
                              unsigned long long* __restrict__ keys) {
  int t = blockIdx.x * 256 + threadIdx.x;
  int n = t / NANCH, k = t - n * NANCH;
  float imh = (float)pimh[0], imw = (float)pimw[0];
  const float* an = out + ANCH_OFF + (size_t)k * 4;
  const float* loc = out + LOCS_OFF + (size_t)t * 4;
  const float* sc = out + SCORES_OFF + (size_t)t * 2;
  float a0 = an[0], a1 = an[1], a2 = an[2], a3 = an[3];
  float ah = __fsub_rn(a2, a0), aw = __fsub_rn(a3, a1);
  float acy = __fadd_rn(a0, 0.5f * ah), acx = __fadd_rn(a1, 0.5f * aw);
  float dy = loc[0], dx = loc[1], dh = loc[2], dw = loc[3];
  float cy = __fadd_rn(__fmul_rn(dy, ah), acy);
  float cx = __fadd_rn(__fmul_rn(dx, aw), acx);
  float hh = __fmul_rn(expf(dh), ah);
  float ww = __fmul_rn(expf(dw), aw);
  float y1 = __fsub_rn(cy, 0.5f * hh), x1 = __fsub_rn(cx, 0.5f * ww);
  float y2 = __fadd_rn(cy, 0.5f * hh), x2 = __fadd_rn(cx, 0.5f * ww);
  y1 = fminf(fmaxf(y1, 0.f), imh); x1 = fminf(fmaxf(x1, 0.f), imw);
  y2 = fminf(fmaxf(y2, 0.f), imh); x2 = fminf(fmaxf(x2, 0.f), imw);
  bool valid = (__fsub_rn(y2, y1) >= 16.f) && (__fsub_rn(x2, x1) >= 16.f);
  float s0 = sc[0], s1 = sc[1];
  float m = fmaxf(s0, s1);
  float e0 = expf(__fsub_rn(s0, m)), e1 = expf(__fsub_rn(s1, m));
  float fg = __fdiv_rn(e1, __fadd_rn(e0, e1));
  float score = valid ? fg : -INFINITY;
  unsigned int u = __float_as_uint(score);
  unsigned int ord = (u & 0x80000000u) ? ~u : (u | 0x80000000u);
  unsigned long long key =
      ((unsigned long long)(~ord) << 16) | (unsigned long long)(k & 0xFFFF);
  float4 b4; b4.x = y1; b4.y = x1; b4.z = y2; b4.w = x2;
  *(float4*)(boxes + (size_t)t * 4) = b4;
  keys[t] = key;
}

// =====================================================================
// Histogram on top-16 key bits (per batch)
// =====================================================================
__global__ void hist_kernel(const unsigned long long* __restrict__ keys,
                            unsigned int* __restrict__ hist) {
  int t = blockIdx.x * 256 + threadIdx.x;
  int n = t / NANCH;
  unsigned int b = (unsigned int)(keys[t] >> 32);
  atomicAdd(&hist[(size_t)n * 65536 + b], 1u);
}

// =====================================================================
// Full exclusive prefix over 65536 buckets (per batch); writes two
// copies (immutable for fixup + mutable for scatter's atomics).
// =====================================================================
__global__ __launch_bounds__(1024) void scanfull_kernel(
    const unsigned int* __restrict__ hist, unsigned int* __restrict__ prefix,
    unsigned int* __restrict__ prefix_mut) {
  int n = blockIdx.x;
  const unsigned int* h = hist + ((size_t)n << 16);
  unsigned int* pf = prefix + ((size_t)n << 16);
  unsigned int* pm = prefix_mut + ((size_t)n << 16);
  __shared__ unsigned int ps[1024];
  int tid = threadIdx.x;
  int base = tid << 6;
  unsigned int s = 0;
  for (int i = 0; i < 64; i++) s += h[base + i];
  ps[tid] = s;
  __syncthreads();
  for (int off = 1; off < 1024; off <<= 1) {
    unsigned int v = ps[tid];
    unsigned int add = (tid >= off) ? ps[tid - off] : 0u;
    __syncthreads();
    ps[tid] = v + add;
    __syncthreads();
  }
  unsigned int run = ps[tid] - s;
  for (int i = 0; i < 64; i++) {
    unsigned int hv = h[base + i];
    pf[base + i] = run;
    pm[base + i] = run;
    run += hv;
  }
}

// =====================================================================
// Scatter into bucket-sorted order (unordered within bucket);
// only the first 8192 positions per batch are kept.
// =====================================================================
__global__ void scatter_kernel(const unsigned long long* __restrict__ keys,
                               unsigned int* __restrict__ prefix_mut,
                               unsigned long long* __restrict__ sorted) {
  int t = blockIdx.x * 256 + threadIdx.x;
  int n = t / NANCH;
  unsigned long long key = keys[t];
  unsigned int b = (unsigned int)(key >> 32);
  unsigned int pos = atomicAdd(&prefix_mut[((size_t)n << 16) + b], 1u);
  if (pos < 8192) sorted[((size_t)n << 13) + pos] = key;
}

// =====================================================================
// Fixup: exact rank within bucket (full 64-bit key compare) -> final
// sorted top-6000 keys + gathered boxes.  7168 threads/batch covers
// boundary buckets up to ~1100 elements (cap 8192).
// =====================================================================
__global__ void fixup_kernel(const unsigned long long* __restrict__ sorted,
                             const unsigned int* __restrict__ prefix,
                             const unsigned int* __restrict__ hist,
                             const float* __restrict__ boxes,
                             unsigned long long* __restrict__ skeys,
                             float* __restrict__ sboxes) {
  int t = blockIdx.x * 256 + threadIdx.x;   // 2*7168
  int n = t / 7168;
  int s = t - n * 7168;
  const unsigned long long* srt = sorted + ((size_t)n << 13);
  unsigned long long key = srt[s];
  unsigned int hi = (unsigned int)(key >> 16);
  if (hi >= 0xFF800000u) {                 // -inf score: order irrelevant
    if (s < NPRE) skeys[(size_t)n * NPRE + s] = key;
    return;
  }
  unsigned int b = (unsigned int)(key >> 32);
  unsigned int st = prefix[((size_t)n << 16) + b];
  if (st >= (unsigned)NPRE) return;
  unsigned int cnt = hist[((size_t)n << 16) + b];
  unsigned int r = 0;
  if (cnt > 1) {
    for (unsigned int j = 0; j < cnt; j++) r += (srt[st + j] < key) ? 1u : 0u;
  }
  unsigned int pos = st + r;
  if (pos < (unsigned)NPRE) {
    skeys[(size_t)n * NPRE + pos] = key;
    int k = (int)(key & 0xFFFFull);
    float4 bx = *(const float4*)(boxes + (((size_t)n * NANCH) + k) * 4);
    *(float4*)(sboxes + ((size_t)n * NPRE + pos) * 4) = bx;
  }
}

// =====================================================================
// Validity bitmask of the 6000 sorted slots: vmask[n][94]
// =====================================================================
__global__ void valid_kernel(const unsigned long long* __restrict__ skeys,
                             unsigned long long* __restrict__ vmask) {
  int n = blockIdx.y;
  int w = blockIdx.x;
  int lane = threadIdx.x;
  int j = w * 64 + lane;
  bool ok = false;
  if (j < NPRE) {
    unsigned int hi = (unsigned int)(skeys[(size_t)n * NPRE + j] >> 16);
    ok = hi < 0xFF800000u;
  }
  unsigned long long m = __ballot(ok);
  if (lane == 0) vmask[(size_t)n * 94 + w] = m;
}

// =====================================================================
// NMS phase A: pairwise suppression bitmask
// =====================================================================
__global__ __launch_bounds__(64) void nms_mask_kernel(
    const float* __restrict__ sboxes, unsigned long long* __restrict__ mask) {
  int n = blockIdx.z;
  int ib = blockIdx.x, jb = blockIdx.y;
  int lane = threadIdx.x;
  __shared__ __align__(16) float jbox[64][4];
  int j = jb * 64 + lane;
  float4 bj4 = (j < NPRE)
                   ? *(const float4*)(sboxes + ((size_t)n * NPRE + j) * 4)
                   : float4{0.f, 0.f, 0.f, 0.f};
  *(float4*)jbox[lane] = bj4;
  __syncthreads();
  int i = ib * 64 + lane;
  if (i >= NPRE) return;
  float4 bi = *(const float4*)(sboxes + ((size_t)n * NPRE + i) * 4);
  float ay1 = bi.x, ax1 = bi.y, ay2 = bi.z, ax2 = bi.w;
  float areaA = __fmul_rn(__fsub_rn(ay2, ay1), __fsub_rn(ax2, ax1));
  unsigned long long bits = 0ull;
#pragma unroll 8
  for (int l = 0; l < 64; l++) {
    float4 bj = *(const float4*)jbox[l];
    float ty1 = fmaxf(ay1, bj.x), tx1 = fmaxf(ax1, bj.y);
    float ty2 = fminf(ay2, bj.z), tx2 = fminf(ax2, bj.w);
    float wh0 = fmaxf(__fsub_rn(ty2, ty1), 0.f);
    float wh1 = fmaxf(__fsub_rn(tx2, tx1), 0.f);
    float inter = __fmul_rn(wh0, wh1);
    float areaB = __fmul_rn(__fsub_rn(bj.z, bj.x), __fsub_rn(bj.w, bj.y));
    float den = __fadd_rn(__fsub_rn(__fadd_rn(areaA, areaB), inter), 1e-9f);
    float iou = __fdiv_rn(inter, den);
    if (iou > 0.7f) bits |= (1ull << l);
  }
  mask[((size_t)n * NPRE + i) * 94 + jb] = bits;
}

// =====================================================================
// NMS phase B: sequential greedy reduce, one wave per batch
// =====================================================================
__global__ __launch_bounds__(64) void nms_reduce_kernel(
    const unsigned long long* __restrict__ mask,
    const unsigned long long* __restrict__ vmask,
    const float* __restrict__ sboxes, float* __restrict__ out) {
  int n = blockIdx.x;
  int lane = threadIdx.x;
  __shared__ int kept[NPOST];
  __shared__ int s_count;

  unsigned long long rlo = ~vmask[(size_t)n * 94 + lane];
  unsigned long long rhi = (64 + lane < 94) ? ~vmask[(size_t)n * 94 + 64 + lane]
                                            : ~0ull;
  int count = 0;
  for (int c = 0; c < 94 && count < NPOST; c++) {
    unsigned long long curw =
        (c < 64) ? __shfl(rlo, c) : __shfl(rhi, c - 64);
    unsigned long long cand = ~curw;
    while (cand != 0ull && count < NPOST) {
      int b = __builtin_ctzll(cand);
      int i = c * 64 + b;
      if (lane == 0) kept[count] = i;
      count++;
      const unsigned long long* row = mask + ((size_t)n * NPRE + i) * 94;
      unsigned long long r0 = row[lane];
      unsigned long long r1 = (64 + lane < 94) ? row[64 + lane] : 0ull;
      rlo |= r0; rhi |= r1;
      curw = (c < 64) ? __shfl(rlo, c) : __shfl(rhi, c - 64);
      cand = ~curw;
      cand &= (b == 63) ? 0ull : (~0ull << (b + 1));
    }
  }
  if (lane == 0) s_count = count;
  __syncthreads();
  count = s_count;

  float* rois = out + ROIS_OFF + (size_t)n * NPOST * 4;
  float* ridx = out + RIDX_OFF + (size_t)n * NPOST;
  for (int s = lane; s < NPOST; s += 64) {
    float4 v = {0.f, 0.f, 0.f, 0.f};
    if (s < count) {
      int i = kept[s];
      v = *(const float4*)(sboxes + ((size_t)n * NPRE + i) * 4);
    }
    *(float4*)(rois + (size_t)s * 4) = v;
    ridx[s] = (float)n;
  }
}

// =====================================================================
extern "C" void kernel_launch(void* const* d_in, const int* in_sizes, int n_in,
                              void* d_out, int out_size, void* d_ws,
                              size_t ws_size, hipStream_t stream) {
  const float* feat = (const float*)d_in[0];
  const float* w1 = (const float*)d_in[1];
  const float* b1 = (const float*)d_in[2];
  const float* sw = (const float*)d_in[3];
  const float* sb = (const float*)d_in[4];
  const float* lw = (const float*)d_in[5];
  const float* lb = (const float*)d_in[6];
  const int* pimh = (const int*)d_in[7];
  const int* pimw = (const int*)d_in[8];
  float* out = (float*)d_out;
  char* ws = (char*)d_ws;

  float* wt = (float*)(ws + WT_OFF);
  float* w54p = (float*)(ws + W54_OFF);
  float* hbuf = (float*)(ws + H_OFF);
  float* boxes = (float*)(ws + BOXES_OFF);
  unsigned long long* keys = (unsigned long long*)(ws + KEYS_OFF);
  unsigned int* hist = (unsigned int*)(ws + HIST_OFF);
  unsigned int* prefix = (unsigned int*)(ws + PREFIX_OFF);
  unsigned int* prefix_mut = (unsigned int*)(ws + PREFIXM_OFF);
  unsigned long long* sorted = (unsigned long long*)(ws + SORTED_OFF);
  unsigned long long* skeys = (unsigned long long*)(ws + SKEYS_OFF);
  float* sboxes = (float*)(ws + SBOXES_OFF);
  unsigned long long* vmask = (unsigned long long*)(ws + VMASK_OFF);
  unsigned long long* nmask = (unsigned long long*)(ws + MASK_OFF);

  hipMemsetAsync(ws + HIST_OFF, 0, 524288, stream);

  transpose_w_kernel<<<dim3(16, 16), dim3(32, 32), 0, stream>>>(w1, wt);
  conv1_kernel<<<dim3(128, 4), 128, 0, stream>>>(feat, wt, b1, hbuf);
  // wt dead; w54p overwrites offset 0
  transpose54_kernel<<<128, 256, 0, stream>>>(lw, sw, w54p);
  heads_kernel<<<128, 256, 0, stream>>>(hbuf, w54p, lb, sb, out);
  anchors_kernel<<<144, 256, 0, stream>>>(out);
  decode_kernel<<<288, 256, 0, stream>>>(out, pimh, pimw, boxes, keys);
  hist_kernel<<<288, 256, 0, stream>>>(keys, hist);
  scanfull_kernel<<<2, 1024, 0, stream>>>(hist, prefix, prefix_mut);
  scatter_kernel<<<288, 256, 0, stream>>>(keys, prefix_mut, sorted);
  fixup_kernel<<<56, 256, 0, stream>>>(sorted, prefix, hist, boxes, skeys,
                                       sboxes);
  valid_kernel<<<dim3(94, 2), 64, 0, stream>>>(skeys, vmask);
  // prefix/sorted dead; nmask overwrites offset 0
  nms_mask_kernel<<<dim3(94, 94, 2), 64, 0, stream>>>(sboxes, nmask);
  nms_reduce_kernel<<<2, 64, 0, stream>>>(nmask, vmask, sboxes, out);
}